// Round 4
// baseline (101.169 us; speedup 1.0000x reference)
//
#include <hip/hip_runtime.h>
#include <hip/hip_bf16.h>
#include <math.h>

// B=8, T=2048, C=1024, H=64.
// out = softmax( (X Wq^T)(X Wk^T)^T * C^-0.5, key mask ) @ (X Wv^T)
//
// Round 4: = Round 3 with two fixes:
//  * BUGFIX: proj V^T store missed the per-batch offset (wrote (h+b)*T+t,
//    reader expects b*H*T + h*T + t). Batches 1-7 read poison -> absmax 0.07.
//  * kf double-buffer via named register arrays + even/odd bodies (rule #20:
//    kf[t&1] runtime-indexed ext-vector array went to scratch).

#define T_SEQ 2048
#define EMB 1024
#define HS 64
#define NB 8

typedef __attribute__((ext_vector_type(8))) short short8;
typedef __attribute__((ext_vector_type(4))) float f32x4;
typedef __attribute__((ext_vector_type(2))) unsigned int uint2_t;
typedef unsigned short ushort_t;

static __device__ inline ushort_t f2bf(float f) {
  union { float f; unsigned u; } v; v.f = f;
  unsigned r = v.u + 0x7FFF + ((v.u >> 16) & 1);  // RNE
  return (ushort_t)(r >> 16);
}
static __device__ inline unsigned pk2(float a, float b) {
  return (unsigned)f2bf(a) | ((unsigned)f2bf(b) << 16);
}

// ---------------- k1: W conversion (48 blocks x 256 thr) ----------------
__global__ __launch_bounds__(256) void convw_kernel(
    const float* __restrict__ Wq, const float* __restrict__ Wk,
    const float* __restrict__ Wv, ushort_t* __restrict__ Wb) {
  const int m = blockIdx.x >> 4;
  const int blk = blockIdx.x & 15;
  const float* src = (m == 0) ? Wq : (m == 1) ? Wk : Wv;
  const float scale = (m == 0) ? 0.03125f : 1.0f;  // fold C^-0.5 into Wq
  const int base = blk * 4096 + threadIdx.x * 16;
  ushort_t* dst = Wb + m * 65536;
  ushort_t tmp[16];
#pragma unroll
  for (int j = 0; j < 4; ++j) {
    float4 x = *(const float4*)(src + base + j * 4);
    tmp[j * 4 + 0] = f2bf(x.x * scale);
    tmp[j * 4 + 1] = f2bf(x.y * scale);
    tmp[j * 4 + 2] = f2bf(x.z * scale);
    tmp[j * 4 + 3] = f2bf(x.w * scale);
  }
  *(short8*)(dst + base) = *(short8*)tmp;
  *(short8*)(dst + base + 8) = *(short8*)(tmp + 8);
}

// ---------------- k2: projections (512 blocks x 256 thr) ----------------
// Block = 32 X-rows (all within one batch: 32 | 2048). X tile staged whole
// (64KB LDS, XOR swizzle), ONE barrier. Wave w owns 48 out cols (ht=3w+t).
__global__ __launch_bounds__(256) void proj_kernel(
    const float* __restrict__ X, const ushort_t* __restrict__ Wb,
    ushort_t* __restrict__ Qb, ushort_t* __restrict__ Kb,
    ushort_t* __restrict__ Vtb) {
  __shared__ __align__(16) ushort_t Xs[32 * 1024];  // 64KB, swizzled rows
  const int tid = threadIdx.x;
  const int lane = tid & 63, w = tid >> 6;
  const int l15 = lane & 15, hi = lane >> 4;
  const long rbase = (long)blockIdx.x * 32;

  // W fragment pointers + first prefetch (global, L2-hot; no barrier dep)
  const ushort_t* Wrow[3];
#pragma unroll
  for (int t = 0; t < 3; ++t) {
    const int ht = 3 * w + t, m = ht >> 2, hs = ht & 3;
    Wrow[t] = Wb + m * 65536 + (hs * 16 + l15) * 1024 + hi * 8;
  }
  short8 wf[2][6];
#pragma unroll
  for (int t = 0; t < 3; ++t) {
    wf[0][2 * t + 0] = *(const short8*)(Wrow[t]);
    wf[0][2 * t + 1] = *(const short8*)(Wrow[t] + 32);
  }

  // stage whole X tile: thread -> row srow, cols (tid&7)*8 + 64*s
  {
    const int srow = tid >> 3, scb = (tid & 7) * 16;  // byte col base
    const int sw = (srow & 7) << 4;
    const float* Xg = X + (rbase + srow) * EMB + (tid & 7) * 8;
    char* Xrow = (char*)Xs + srow * 2048;
#pragma unroll
    for (int s = 0; s < 16; ++s) {
      float4 a = *(const float4*)(Xg + s * 64);
      float4 b = *(const float4*)(Xg + s * 64 + 4);
      ushort_t tmp[8];
      tmp[0] = f2bf(a.x); tmp[1] = f2bf(a.y);
      tmp[2] = f2bf(a.z); tmp[3] = f2bf(a.w);
      tmp[4] = f2bf(b.x); tmp[5] = f2bf(b.y);
      tmp[6] = f2bf(b.z); tmp[7] = f2bf(b.w);
      *(short8*)(Xrow + ((scb + s * 128) ^ sw)) = *(short8*)tmp;
    }
  }
  __syncthreads();

  f32x4 acc[2][3];
#pragma unroll
  for (int rt = 0; rt < 2; ++rt)
#pragma unroll
    for (int t = 0; t < 3; ++t) acc[rt][t] = (f32x4){0.f, 0.f, 0.f, 0.f};

  const int swA = (l15 & 7) << 4;
#pragma unroll
  for (int s = 0; s < 16; ++s) {
    if (s < 15) {  // prefetch next W frags
#pragma unroll
      for (int t = 0; t < 3; ++t) {
        wf[(s + 1) & 1][2 * t + 0] = *(const short8*)(Wrow[t] + (s + 1) * 64);
        wf[(s + 1) & 1][2 * t + 1] = *(const short8*)(Wrow[t] + (s + 1) * 64 + 32);
      }
    }
#pragma unroll
    for (int rt = 0; rt < 2; ++rt) {
      const char* Xrow = (const char*)Xs + (rt * 16 + l15) * 2048;
      short8 a0 = *(const short8*)(Xrow + ((s * 128 + hi * 16) ^ swA));
      short8 a1 = *(const short8*)(Xrow + ((s * 128 + 64 + hi * 16) ^ swA));
#pragma unroll
      for (int t = 0; t < 3; ++t) {
        acc[rt][t] = __builtin_amdgcn_mfma_f32_16x16x32_bf16(
            a0, wf[s & 1][2 * t + 0], acc[rt][t], 0, 0, 0);
        acc[rt][t] = __builtin_amdgcn_mfma_f32_16x16x32_bf16(
            a1, wf[s & 1][2 * t + 1], acc[rt][t], 0, 0, 0);
      }
    }
  }

  // epilogue: D col=l15, row=4*hi+reg. Q/K row-major [B*T][64];
  // V stored transposed PER BATCH: Vtb[b][h][t]  (<-- round-3 bug was here)
  const long bblk = rbase >> 11;          // batch of this block
  const long tb0 = rbase & 2047;          // t-offset within batch
  ushort_t* outs[2] = {Qb, Kb};
#pragma unroll
  for (int rt = 0; rt < 2; ++rt)
#pragma unroll
    for (int t = 0; t < 3; ++t) {
      const int ht = 3 * w + t, m = ht >> 2, hs = ht & 3;
      const int h = hs * 16 + l15;
      if (m < 2) {
#pragma unroll
        for (int r = 0; r < 4; ++r) {
          const long row = rbase + rt * 16 + 4 * hi + r;
          outs[m][row * 64 + h] = f2bf(acc[rt][t][r]);
        }
      } else {
        const long tloc = tb0 + rt * 16 + 4 * hi;  // t within batch
        uint2_t v;
        v.x = pk2(acc[rt][t][0], acc[rt][t][1]);
        v.y = pk2(acc[rt][t][2], acc[rt][t][3]);
        *(uint2_t*)(Vtb + bblk * (long)HS * T_SEQ + (long)h * T_SEQ + tloc) = v;
      }
    }
}

// ---------------- k3: attention (256 blocks x 512 thr) ----------------
__global__ __launch_bounds__(512, 2) void attn_kernel(
    const ushort_t* __restrict__ Qb, const ushort_t* __restrict__ Kb,
    const ushort_t* __restrict__ Vtb, const int* __restrict__ mask,
    float* __restrict__ out) {
  __shared__ __align__(16) float biasLds[T_SEQ];       // 8KB
  __shared__ __align__(16) ushort_t Ps[8 * 1024];      // 16KB: per-wave 16x64 swz
  __shared__ __align__(16) float mergeLds[256 * 18];   // 18KB

  const int tid = threadIdx.x;
  const int lane = tid & 63, w = tid >> 6;
  const int l15 = lane & 15, hi = lane >> 4;
  const int qsub = w & 3, half = w >> 2;
  const int id = blockIdx.x;
  const int b = id & 7, qb = id >> 3;  // one batch per XCD (L2 locality)

  // stage mask bias once (512 thr x int4)
  {
    int4 mi = *(const int4*)(mask + b * T_SEQ + tid * 4);
    float4 bv = {mi.x ? -1e30f : 0.f, mi.y ? -1e30f : 0.f,
                 mi.z ? -1e30f : 0.f, mi.w ? -1e30f : 0.f};
    *(float4*)(biasLds + tid * 4) = bv;
  }

  // Q fragments (16 queries per wave, held in regs)
  const ushort_t* Qrow = Qb + (long)(b * T_SEQ + qb * 64 + qsub * 16 + l15) * 64;
  const short8 qf0 = *(const short8*)(Qrow + hi * 8);
  const short8 qf1 = *(const short8*)(Qrow + 32 + hi * 8);

  const ushort_t* Kg = Kb + (long)b * T_SEQ * 64;
  const ushort_t* Vg = Vtb + (long)b * HS * T_SEQ;
  const int t0 = half * 16;  // this wave's 16 K-tiles (64 keys each)

  // per-lane global fragment bases
  const ushort_t* kbase = Kg + ((long)t0 * 64 + l15) * 64 + hi * 8;
  const ushort_t* vbase = Vg + (long)l15 * T_SEQ + t0 * 64 + hi * 8;

  short8 kfA[8], kfB[8];  // named double buffers -> registers (rule #20)
#pragma unroll
  for (int kt = 0; kt < 4; ++kt) {
    kfA[kt * 2 + 0] = *(const short8*)(kbase + kt * 1024);
    kfA[kt * 2 + 1] = *(const short8*)(kbase + kt * 1024 + 32);
  }

  f32x4 O[4];
#pragma unroll
  for (int ht = 0; ht < 4; ++ht) O[ht] = (f32x4){0.f, 0.f, 0.f, 0.f};
  float mrow = -1e30f, lsum = 0.f;

  char* prow = (char*)(Ps + w * 1024) + l15 * 128;
  const int sw = (l15 & 7) << 4;

  __syncthreads();  // bias visible

  auto tile_step = [&](const int t, short8 (&kcur)[8], short8 (&knxt)[8]) {
    // V fragments for this tile (issue early; consumed after softmax)
    short8 vf[8];
#pragma unroll
    for (int ht = 0; ht < 4; ++ht) {
      vf[ht * 2 + 0] = *(const short8*)(vbase + (long)ht * 16 * T_SEQ + t * 64);
      vf[ht * 2 + 1] = *(const short8*)(vbase + (long)ht * 16 * T_SEQ + t * 64 + 32);
    }

    // S^T = K.Q^T : col(l15)=query, row(4hi+r)=key (within kt tile)
    f32x4 s[4];
    __builtin_amdgcn_s_setprio(1);
#pragma unroll
    for (int kt = 0; kt < 4; ++kt) {
      f32x4 z = {0.f, 0.f, 0.f, 0.f};
      s[kt] = __builtin_amdgcn_mfma_f32_16x16x32_bf16(kcur[kt * 2 + 0], qf0, z, 0, 0, 0);
      s[kt] = __builtin_amdgcn_mfma_f32_16x16x32_bf16(kcur[kt * 2 + 1], qf1, s[kt], 0, 0, 0);
    }
    __builtin_amdgcn_s_setprio(0);

    // prefetch next K tile into other buffer
    if (t < 15) {
      const ushort_t* kb2 = kbase + (long)(t + 1) * 4096;
#pragma unroll
      for (int kt = 0; kt < 4; ++kt) {
        knxt[kt * 2 + 0] = *(const short8*)(kb2 + kt * 1024);
        knxt[kt * 2 + 1] = *(const short8*)(kb2 + kt * 1024 + 32);
      }
    }

    // bias + per-lane online softmax (query l15; keys spread over hi groups)
    const float* bl = biasLds + (t0 + t) * 64;
#pragma unroll
    for (int kt = 0; kt < 4; ++kt) s[kt] += *(const f32x4*)(bl + kt * 16 + hi * 4);

    float mt = -1e30f;
#pragma unroll
    for (int kt = 0; kt < 4; ++kt)
#pragma unroll
      for (int r = 0; r < 4; ++r) mt = fmaxf(mt, s[kt][r]);
    mt = fmaxf(mt, __shfl_xor(mt, 16, 64));
    mt = fmaxf(mt, __shfl_xor(mt, 32, 64));
    const float mnew = fmaxf(mrow, mt);
    const float alpha = __expf(mrow - mnew);
    float psum = 0.f;
#pragma unroll
    for (int kt = 0; kt < 4; ++kt) {
      const float p0 = __expf(s[kt][0] - mnew);
      const float p1 = __expf(s[kt][1] - mnew);
      const float p2 = __expf(s[kt][2] - mnew);
      const float p3 = __expf(s[kt][3] - mnew);
      psum += (p0 + p1) + (p2 + p3);
      const int a0 = (kt * 32 + hi * 8) ^ sw;
      *(unsigned*)(prow + a0) = pk2(p0, p1);
      *(unsigned*)(prow + a0 + 4) = pk2(p2, p3);
    }
    lsum = lsum * alpha + psum;
    mrow = mnew;

    // rescale O (row r of O = query 4hi+r)
#pragma unroll
    for (int r = 0; r < 4; ++r) {
      const float ar = __shfl(alpha, 4 * hi + r, 64);
#pragma unroll
      for (int ht = 0; ht < 4; ++ht) O[ht][r] *= ar;
    }

    // PV: A = P rows (q=l15), B = V^T rows (h); within-wave LDS roundtrip
    short8 pa0 = *(const short8*)(prow + ((hi * 16) ^ sw));
    short8 pa1 = *(const short8*)(prow + ((64 + hi * 16) ^ sw));
    __builtin_amdgcn_s_setprio(1);
#pragma unroll
    for (int ht = 0; ht < 4; ++ht) {
      O[ht] = __builtin_amdgcn_mfma_f32_16x16x32_bf16(pa0, vf[ht * 2 + 0], O[ht], 0, 0, 0);
      O[ht] = __builtin_amdgcn_mfma_f32_16x16x32_bf16(pa1, vf[ht * 2 + 1], O[ht], 0, 0, 0);
    }
    __builtin_amdgcn_s_setprio(0);
  };

  for (int t = 0; t < 16; t += 2) {
    tile_step(t, kfA, kfB);
    tile_step(t + 1, kfB, kfA);
  }

  // total l per query (reduce over hi groups)
  lsum += __shfl_xor(lsum, 16, 64);
  lsum += __shfl_xor(lsum, 32, 64);

  // merge KV halves: waves 4-7 publish, waves 0-3 combine + store
  if (w >= 4) {
    float* ml = mergeLds + ((w - 4) * 64 + lane) * 18;
    ml[0] = mrow; ml[1] = lsum;
#pragma unroll
    for (int ht = 0; ht < 4; ++ht)
#pragma unroll
      for (int r = 0; r < 4; ++r) ml[2 + ht * 4 + r] = O[ht][r];
  }
  __syncthreads();
  if (w < 4) {
    const float* ml = mergeLds + (w * 64 + lane) * 18;
    const float mB = ml[0], lB = ml[1];
    const float mn = fmaxf(mrow, mB);
    const float aa = __expf(mrow - mn);
    const float ab = __expf(mB - mn);
    const float inv = 1.0f / (lsum * aa + lB * ab);
    float* ob = out + (long)(b * T_SEQ + qb * 64 + qsub * 16) * 64;
#pragma unroll
    for (int r = 0; r < 4; ++r) {
      const float aar = __shfl(aa, 4 * hi + r, 64);
      const float abr = __shfl(ab, 4 * hi + r, 64);
      const float invr = __shfl(inv, 4 * hi + r, 64);
#pragma unroll
      for (int ht = 0; ht < 4; ++ht)
        ob[(4 * hi + r) * 64 + ht * 16 + l15] =
            (O[ht][r] * aar + ml[2 + ht * 4 + r] * abr) * invr;
    }
  }
}

// ---------------- launch ----------------
extern "C" void kernel_launch(void* const* d_in, const int* in_sizes, int n_in,
                              void* d_out, int out_size, void* d_ws, size_t ws_size,
                              hipStream_t stream) {
  const float* X  = (const float*)d_in[0];
  const float* Wq = (const float*)d_in[1];
  const float* Wk = (const float*)d_in[2];
  const float* Wv = (const float*)d_in[3];
  const int* mask = (const int*)d_in[4];
  float* outp = (float*)d_out;

  const long NT = (long)NB * T_SEQ * HS;
  ushort_t* wsb = (ushort_t*)d_ws;
  ushort_t* Qb  = wsb;            // 2 MB
  ushort_t* Kb  = wsb + NT;       // 2 MB
  ushort_t* Vtb = wsb + 2 * NT;   // 2 MB (per-batch transposed V)
  ushort_t* Wb  = wsb + 3 * NT;   // 384 KB

  convw_kernel<<<48, 256, 0, stream>>>(Wq, Wk, Wv, Wb);
  proj_kernel<<<(NB * T_SEQ) / 32, 256, 0, stream>>>(X, Wb, Qb, Kb, Vtb);
  attn_kernel<<<256, 512, 0, stream>>>(Qb, Kb, Vtb, mask, outp);
}